// Round 1
// baseline (1964.874 us; speedup 1.0000x reference)
//
#include <hip/hip_runtime.h>

// Problem constants (fixed by reference)
#define NU 100000
#define NI 50000
#define NN 150000          // NU + NI
#define DIM 128
#define NHOPS 3
#define STR ((NHOPS + 1) * DIM)   // 512 floats per node in d_out

// ---------------- CSR build ----------------

__global__ void hist_kernel(const int* __restrict__ rows, int* deg, int E) {
  int i = blockIdx.x * blockDim.x + threadIdx.x;
  int stride = gridDim.x * blockDim.x;
  for (; i < E; i += stride) atomicAdd(&deg[rows[i]], 1);
}

// 3-kernel multi-block exclusive scan over NN degrees.
// k1: per-block (2048-elem) sums.  k2: serial scan of ~74 block sums.
// k3: local scan + block offset -> rstart & cursor.
__global__ void scan_k1(const int* __restrict__ deg, int* bsum, int n) {
  __shared__ int red[256];
  int b = blockIdx.x, t = threadIdx.x;
  int base = b * 2048 + t * 8;
  int s = 0;
#pragma unroll
  for (int j = 0; j < 8; ++j) { int i = base + j; if (i < n) s += deg[i]; }
  red[t] = s;
  __syncthreads();
  for (int off = 128; off > 0; off >>= 1) {
    if (t < off) red[t] += red[t + off];
    __syncthreads();
  }
  if (t == 0) bsum[b] = red[0];
}

__global__ void scan_k2(int* bsum, int nb) {
  if (threadIdx.x == 0) {
    int run = 0;
    for (int i = 0; i < nb; ++i) { int v = bsum[i]; bsum[i] = run; run += v; }
  }
}

__global__ void scan_k3(const int* __restrict__ deg, const int* __restrict__ bsum,
                        int* __restrict__ rstart, int* __restrict__ cursor, int n, int E) {
  __shared__ int red[256];
  int b = blockIdx.x, t = threadIdx.x;
  int base = b * 2048 + t * 8;
  int loc[8];
  int s = 0;
#pragma unroll
  for (int j = 0; j < 8; ++j) {
    int i = base + j;
    int d = (i < n) ? deg[i] : 0;
    loc[j] = s; s += d;
  }
  red[t] = s;
  __syncthreads();
  for (int off = 1; off < 256; off <<= 1) {
    int v = (t >= off) ? red[t - off] : 0;
    __syncthreads();
    red[t] += v;
    __syncthreads();
  }
  int toff = bsum[b] + red[t] - s;  // exclusive prefix for this thread
#pragma unroll
  for (int j = 0; j < 8; ++j) {
    int i = base + j;
    if (i < n) { int v = toff + loc[j]; rstart[i] = v; cursor[i] = v; }
  }
  if (b == 0 && t == 0) rstart[n] = E;
}

// Interleaved 8B CSR entry: .x = col, .y = val bits. One store per edge.
__global__ void scatter_kernel(const int* __restrict__ rows, const int* __restrict__ cols,
                               const float* __restrict__ vals, int* cursor,
                               int2* __restrict__ csr, int E) {
  int i = blockIdx.x * blockDim.x + threadIdx.x;
  int stride = gridDim.x * blockDim.x;
  for (; i < E; i += stride) {
    int r = rows[i];
    int p = atomicAdd(&cursor[r], 1);
    int2 e; e.x = cols[i]; e.y = __float_as_int(vals[i]);
    csr[p] = e;
  }
}

// ---------------- dense kernels ----------------

// raw concat -> rawA (stride DIM, compact); scaled ego (t*embed) -> out slot 0.
__global__ void copy_embed_fused(const float* __restrict__ ue, const float* __restrict__ ie,
                                 const float* __restrict__ ut, const float* __restrict__ it,
                                 float* __restrict__ rawA, float* __restrict__ out) {
  int idx = blockIdx.x * blockDim.x + threadIdx.x;  // float4 index, NN*DIM/4 total
  if (idx >= NN * (DIM / 4)) return;
  int node = idx >> 5;   // 32 float4 per node
  int d4 = idx & 31;
  float t;
  float4 x;
  if (node < NU) { t = ut[node]; x = ((const float4*)(ue + (size_t)node * DIM))[d4]; }
  else { t = it[node - NU]; x = ((const float4*)(ie + (size_t)(node - NU) * DIM))[d4]; }
  ((float4*)(rawA + (size_t)node * DIM))[d4] = x;
  float4 y; y.x = x.x * t; y.y = x.y * t; y.z = x.z * t; y.w = x.w * t;
  ((float4*)(out + (size_t)node * STR))[d4] = y;
}

// Fallback: raw concat -> out slot 0 only (epilogue scales later).
__global__ void copy_embed_raw(const float* __restrict__ ue, const float* __restrict__ ie,
                               float* __restrict__ out) {
  int idx = blockIdx.x * blockDim.x + threadIdx.x;
  if (idx >= NN * (DIM / 4)) return;
  int node = idx >> 5;
  int d4 = idx & 31;
  const float4* src = (node < NU)
      ? ((const float4*)(ue + (size_t)node * DIM) + d4)
      : ((const float4*)(ie + (size_t)(node - NU) * DIM) + d4);
  ((float4*)(out + (size_t)node * STR))[d4] = *src;
}

// 2 rows per wave: each 32-lane half owns one row, lane owns 4 dims (float4).
// Halves the per-edge instruction overhead (gather loads + shuffles) vs the
// 1-row/wave float2 version; same bytes moved, same 512B/row coalescing.
__global__ __launch_bounds__(256) void spmm_kernel(
    const int* __restrict__ row_start, const int2* __restrict__ csr,
    const float* __restrict__ src, int src_str,
    float* raw_out, int raw_str,
    float* scaled_out, int scaled_str,
    const float* __restrict__ ut, const float* __restrict__ it, int hop) {
  int wave = (blockIdx.x * blockDim.x + threadIdx.x) >> 6;
  if (wave >= NN / 2) return;   // wave-uniform exit (NN is even)
  int lane = threadIdx.x & 63;
  int half = lane >> 5;         // which row of the pair this lane serves
  int lane_in = lane & 31;      // lane within half; owns dims [4*lane_in, 4*lane_in+4)
  int row = wave * 2 + half;
  int s = row_start[row];
  int e = row_start[row + 1];
  float ax = 0.f, ay = 0.f, az = 0.f, aw = 0.f;
  const float* src_base = src + lane_in * 4;
  int p = s;
  for (; p + 8 <= e; p += 8) {
    int2 ed = csr[p + (lane_in & 7)];
#pragma unroll
    for (int j = 0; j < 8; ++j) {
      int cc = __shfl(ed.x, j, 32);                     // broadcast within half
      float vv = __int_as_float(__shfl(ed.y, j, 32));
      float4 x = *(const float4*)(src_base + (size_t)cc * src_str);
      ax += vv * x.x; ay += vv * x.y; az += vv * x.z; aw += vv * x.w;
    }
  }
  for (; p < e; ++p) {
    int2 ed = csr[p];           // uniform within half -> broadcast load
    float4 x = *(const float4*)(src_base + (size_t)ed.x * src_str);
    float vv = __int_as_float(ed.y);
    ax += vv * x.x; ay += vv * x.y; az += vv * x.z; aw += vv * x.w;
  }
  if (raw_out) {
    float4 o; o.x = ax; o.y = ay; o.z = az; o.w = aw;
    *(float4*)(raw_out + (size_t)row * raw_str + lane_in * 4) = o;
  }
  if (scaled_out) {
    float t = (row < NU) ? ut[row] : it[row - NU];
    float sc = t;
    for (int j = 0; j < hop; ++j) sc *= (1.f - t);
    float4 o; o.x = ax * sc; o.y = ay * sc; o.z = az * sc; o.w = aw * sc;
    *(float4*)(scaled_out + (size_t)row * scaled_str + lane_in * 4) = o;
  }
}

// Fallback epilogue: scale slots 0..2 in place by t*(1-t)^k.
__global__ void epilogue_kernel(const float* __restrict__ ut, const float* __restrict__ it,
                                float* __restrict__ out) {
  int idx = blockIdx.x * blockDim.x + threadIdx.x;  // float4 units, NN * 96 total
  if (idx >= NN * 96) return;
  int node = idx / 96;
  int rem = idx - node * 96;
  int k = rem >> 5;        // slot 0..2
  int d4 = rem & 31;
  float t = (node < NU) ? ut[node] : it[node - NU];
  float dcy = 1.f - t;
  float sc = t;
  for (int j = 0; j < k; ++j) sc *= dcy;
  float4* p = (float4*)(out + (size_t)node * STR + k * DIM) + d4;
  float4 x = *p;
  x.x *= sc; x.y *= sc; x.z *= sc; x.w *= sc;
  *p = x;
}

// ---------------- launch ----------------

extern "C" void kernel_launch(void* const* d_in, const int* in_sizes, int n_in,
                              void* d_out, int out_size, void* d_ws, size_t ws_size,
                              hipStream_t stream) {
  const float* ue = (const float*)d_in[0];
  const float* ie = (const float*)d_in[1];
  const float* ut = (const float*)d_in[2];
  const float* it = (const float*)d_in[3];
  const float* vals = (const float*)d_in[4];
  const int* rows = (const int*)d_in[5];
  const int* cols = (const int*)d_in[6];
  float* out = (float*)d_out;
  const int E = in_sizes[4];

  size_t off = 0;
  auto alloc = [&](size_t bytes) {
    void* p = (char*)d_ws + off;
    off += (bytes + 255) & ~(size_t)255;
    return p;
  };
  int* deg = (int*)alloc((size_t)NN * 4);
  int* cursor = (int*)alloc((size_t)NN * 4);
  int* rstart = (int*)alloc(((size_t)NN + 1) * 4);
  int* bsum = (int*)alloc(1024 * 4);
  int2* csr = (int2*)alloc((size_t)E * 8);
  size_t csr_end = off;
  float* rawA = (float*)alloc((size_t)NN * DIM * 4);
  float* rawB = (float*)alloc((size_t)NN * DIM * 4);
  bool use_csr = (csr_end <= ws_size);
  bool use_compact = (off <= ws_size);

  const int n4_embed = NN * (DIM / 4);
  const int nb_scan = (NN + 2047) / 2048;
  const int spmm_blocks = (NN / 2 + 3) / 4;   // 4 waves/block, 2 rows/wave

  if (use_csr) {
    // ---- CSR build ----
    hipMemsetAsync(deg, 0, (size_t)NN * 4, stream);
    hist_kernel<<<2048, 256, 0, stream>>>(rows, deg, E);
    scan_k1<<<nb_scan, 256, 0, stream>>>(deg, bsum, NN);
    scan_k2<<<1, 64, 0, stream>>>(bsum, nb_scan);
    scan_k3<<<nb_scan, 256, 0, stream>>>(deg, bsum, rstart, cursor, NN, E);
    scatter_kernel<<<2048, 256, 0, stream>>>(rows, cols, vals, cursor, csr, E);

    if (use_compact) {
      // primary path: compact raw ping-pong in ws, scaled writes fused
      copy_embed_fused<<<(n4_embed + 255) / 256, 256, 0, stream>>>(ue, ie, ut, it, rawA, out);
      float* rin = rawA;
      float* rout = rawB;
      for (int h = 1; h <= NHOPS; ++h) {
        float* raw_dst = (h < NHOPS) ? rout : nullptr;  // last hop: no raw consumer
        spmm_kernel<<<spmm_blocks, 256, 0, stream>>>(rstart, csr, rin, DIM,
                                                     raw_dst, DIM,
                                                     out + h * DIM, STR, ut, it, h);
        float* tmp = rin; rin = rout; rout = tmp;
      }
    } else {
      // fallback: raw slots in d_out, epilogue scales slots 0..2
      copy_embed_raw<<<(n4_embed + 255) / 256, 256, 0, stream>>>(ue, ie, out);
      for (int h = 1; h <= NHOPS; ++h) {
        float* raw_dst = (h < NHOPS) ? (out + h * DIM) : nullptr;
        float* sc_dst = (h == NHOPS) ? (out + h * DIM) : nullptr;
        spmm_kernel<<<spmm_blocks, 256, 0, stream>>>(rstart, csr, out + (h - 1) * DIM, STR,
                                                     raw_dst, STR, sc_dst, STR, ut, it, h);
      }
      epilogue_kernel<<<(NN * 96 + 255) / 256, 256, 0, stream>>>(ut, it, out);
    }
  }
  // (no atomic fallback: harness guarantees a usable ws; CSR needs only ~40MB)
}

// Round 2
// 1885.186 us; speedup vs baseline: 1.0423x; 1.0423x over previous
//
#include <hip/hip_runtime.h>

// Problem constants (fixed by reference)
#define NU 100000
#define NI 50000
#define NN 150000          // NU + NI
#define DIM 128
#define NHOPS 3
#define STR ((NHOPS + 1) * DIM)   // 512 floats per node in d_out

// Bucketed CSR build: bucket = row>>7 (128 rows per bucket), 8 sub-cursors
// per bucket keyed by blockIdx&7 (approx. XCD) so each append region is
// written by one L2 -> full-line evictions, ~1x write amplification.
#define NBK 1172            // ceil(NN / 128)
#define NSUB 8
#define NBINS (NBK * NSUB)  // 9376
#define PART_GRID 1024      // bucket_hist and bucket_scatter MUST share this

// ---------------- CSR build (fallback path kernels) ----------------

__global__ void hist_kernel(const int* __restrict__ rows, int* deg, int E) {
  int i = blockIdx.x * blockDim.x + threadIdx.x;
  int stride = gridDim.x * blockDim.x;
  for (; i < E; i += stride) atomicAdd(&deg[rows[i]], 1);
}

__global__ void scatter_kernel(const int* __restrict__ rows, const int* __restrict__ cols,
                               const float* __restrict__ vals, int* cursor,
                               int2* __restrict__ csr, int E) {
  int i = blockIdx.x * blockDim.x + threadIdx.x;
  int stride = gridDim.x * blockDim.x;
  for (; i < E; i += stride) {
    int r = rows[i];
    int p = atomicAdd(&cursor[r], 1);
    int2 e; e.x = cols[i]; e.y = __float_as_int(vals[i]);
    csr[p] = e;
  }
}

// ---------------- scan machinery (shared) ----------------
// 3-kernel multi-block exclusive scan over n counters.
__global__ void scan_k1(const int* __restrict__ deg, int* bsum, int n) {
  __shared__ int red[256];
  int b = blockIdx.x, t = threadIdx.x;
  int base = b * 2048 + t * 8;
  int s = 0;
#pragma unroll
  for (int j = 0; j < 8; ++j) { int i = base + j; if (i < n) s += deg[i]; }
  red[t] = s;
  __syncthreads();
  for (int off = 128; off > 0; off >>= 1) {
    if (t < off) red[t] += red[t + off];
    __syncthreads();
  }
  if (t == 0) bsum[b] = red[0];
}

__global__ void scan_k2(int* bsum, int nb) {
  if (threadIdx.x == 0) {
    int run = 0;
    for (int i = 0; i < nb; ++i) { int v = bsum[i]; bsum[i] = run; run += v; }
  }
}

__global__ void scan_k3(const int* __restrict__ deg, const int* __restrict__ bsum,
                        int* __restrict__ rstart, int* __restrict__ cursor, int n, int E) {
  __shared__ int red[256];
  int b = blockIdx.x, t = threadIdx.x;
  int base = b * 2048 + t * 8;
  int loc[8];
  int s = 0;
#pragma unroll
  for (int j = 0; j < 8; ++j) {
    int i = base + j;
    int d = (i < n) ? deg[i] : 0;
    loc[j] = s; s += d;
  }
  red[t] = s;
  __syncthreads();
  for (int off = 1; off < 256; off <<= 1) {
    int v = (t >= off) ? red[t - off] : 0;
    __syncthreads();
    red[t] += v;
    __syncthreads();
  }
  int toff = bsum[b] + red[t] - s;  // exclusive prefix for this thread
#pragma unroll
  for (int j = 0; j < 8; ++j) {
    int i = base + j;
    if (i < n) { int v = toff + loc[j]; rstart[i] = v; cursor[i] = v; }
  }
  if (b == 0 && t == 0) rstart[n] = E;
}

// ---------------- bucketed CSR build (primary path) ----------------

// Per-(bucket,sub) histogram. LDS-privatized per block; sub = blockIdx&7.
// Grid MUST match bucket_scatter (same edge->block mapping => same sub).
__global__ void bucket_hist(const int* __restrict__ rows, int* bdeg, int E) {
  __shared__ int h[NBK];
  for (int j = threadIdx.x; j < NBK; j += blockDim.x) h[j] = 0;
  __syncthreads();
  int i = blockIdx.x * blockDim.x + threadIdx.x;
  int stride = gridDim.x * blockDim.x;
  for (; i < E; i += stride) atomicAdd(&h[rows[i] >> 7], 1);
  __syncthreads();
  int sub = blockIdx.x & (NSUB - 1);
  for (int j = threadIdx.x; j < NBK; j += blockDim.x) {
    int v = h[j];
    if (v) atomicAdd(&bdeg[j * NSUB + sub], v);
  }
}

// Append edges into their (bucket,sub) region. Appends hit ~9K hot lines
// (L2-resident), each region written by one XCD -> full-line evictions.
__global__ void bucket_scatter(const int* __restrict__ rows, const int* __restrict__ cols,
                               const float* __restrict__ vals, int* bcursor,
                               int* __restrict__ brow, int2* __restrict__ bcv, int E) {
  int sub = blockIdx.x & (NSUB - 1);
  int i = blockIdx.x * blockDim.x + threadIdx.x;
  int stride = gridDim.x * blockDim.x;
  for (; i < E; i += stride) {
    int r = rows[i];
    int p = atomicAdd(&bcursor[(r >> 7) * NSUB + sub], 1);
    brow[p] = r;
    int2 e2; e2.x = cols[i]; e2.y = __float_as_int(vals[i]);
    bcv[p] = e2;
  }
}

// Row degrees via per-bucket LDS histogram; zero global atomics.
// Block b owns rows [b*128, b*128+128) exclusively.
__global__ void deg_from_buckets(const int* __restrict__ boff, const int* __restrict__ brow,
                                 int* __restrict__ deg) {
  __shared__ int h[128];
  int b = blockIdx.x;
  if (threadIdx.x < 128) h[threadIdx.x] = 0;
  __syncthreads();
  int base = b * 128;
  int s = boff[b * NSUB];
  int e = boff[b * NSUB + NSUB];
  for (int i = s + threadIdx.x; i < e; i += blockDim.x)
    atomicAdd(&h[brow[i] - base], 1);
  __syncthreads();
  if (threadIdx.x < 128) {
    int r = base + threadIdx.x;
    if (r < NN) deg[r] = h[threadIdx.x];
  }
}

// Final placement: block b reads its bucket segment sequentially and
// scatters within its private ~32KB CSR window (L2-local atomics+stores).
__global__ void csr_from_buckets(const int* __restrict__ boff, const int* __restrict__ brow,
                                 const int2* __restrict__ bcv, int* cursor,
                                 int2* __restrict__ csr) {
  int b = blockIdx.x;
  int s = boff[b * NSUB];
  int e = boff[b * NSUB + NSUB];
  for (int i = s + threadIdx.x; i < e; i += blockDim.x) {
    int r = brow[i];
    int p = atomicAdd(&cursor[r], 1);
    csr[p] = bcv[i];
  }
}

// ---------------- dense kernels ----------------

// raw concat -> rawA (stride DIM, compact); scaled ego (t*embed) -> out slot 0.
__global__ void copy_embed_fused(const float* __restrict__ ue, const float* __restrict__ ie,
                                 const float* __restrict__ ut, const float* __restrict__ it,
                                 float* __restrict__ rawA, float* __restrict__ out) {
  int idx = blockIdx.x * blockDim.x + threadIdx.x;  // float4 index, NN*DIM/4 total
  if (idx >= NN * (DIM / 4)) return;
  int node = idx >> 5;   // 32 float4 per node
  int d4 = idx & 31;
  float t;
  float4 x;
  if (node < NU) { t = ut[node]; x = ((const float4*)(ue + (size_t)node * DIM))[d4]; }
  else { t = it[node - NU]; x = ((const float4*)(ie + (size_t)(node - NU) * DIM))[d4]; }
  ((float4*)(rawA + (size_t)node * DIM))[d4] = x;
  float4 y; y.x = x.x * t; y.y = x.y * t; y.z = x.z * t; y.w = x.w * t;
  ((float4*)(out + (size_t)node * STR))[d4] = y;
}

// Fallback: raw concat -> out slot 0 only (epilogue scales later).
__global__ void copy_embed_raw(const float* __restrict__ ue, const float* __restrict__ ie,
                               float* __restrict__ out) {
  int idx = blockIdx.x * blockDim.x + threadIdx.x;
  if (idx >= NN * (DIM / 4)) return;
  int node = idx >> 5;
  int d4 = idx & 31;
  const float4* src = (node < NU)
      ? ((const float4*)(ue + (size_t)node * DIM) + d4)
      : ((const float4*)(ie + (size_t)(node - NU) * DIM) + d4);
  ((float4*)(out + (size_t)node * STR))[d4] = *src;
}

// 2 rows per wave: each 32-lane half owns one row, lane owns 4 dims (float4).
__global__ __launch_bounds__(256) void spmm_kernel(
    const int* __restrict__ row_start, const int2* __restrict__ csr,
    const float* __restrict__ src, int src_str,
    float* raw_out, int raw_str,
    float* scaled_out, int scaled_str,
    const float* __restrict__ ut, const float* __restrict__ it, int hop) {
  int wave = (blockIdx.x * blockDim.x + threadIdx.x) >> 6;
  if (wave >= NN / 2) return;   // wave-uniform exit (NN is even)
  int lane = threadIdx.x & 63;
  int half = lane >> 5;         // which row of the pair this lane serves
  int lane_in = lane & 31;      // lane within half; owns dims [4*lane_in, 4*lane_in+4)
  int row = wave * 2 + half;
  int s = row_start[row];
  int e = row_start[row + 1];
  float ax = 0.f, ay = 0.f, az = 0.f, aw = 0.f;
  const float* src_base = src + lane_in * 4;
  int p = s;
  for (; p + 8 <= e; p += 8) {
    int2 ed = csr[p + (lane_in & 7)];
#pragma unroll
    for (int j = 0; j < 8; ++j) {
      int cc = __shfl(ed.x, j, 32);                     // broadcast within half
      float vv = __int_as_float(__shfl(ed.y, j, 32));
      float4 x = *(const float4*)(src_base + (size_t)cc * src_str);
      ax += vv * x.x; ay += vv * x.y; az += vv * x.z; aw += vv * x.w;
    }
  }
  for (; p < e; ++p) {
    int2 ed = csr[p];           // uniform within half -> broadcast load
    float4 x = *(const float4*)(src_base + (size_t)ed.x * src_str);
    float vv = __int_as_float(ed.y);
    ax += vv * x.x; ay += vv * x.y; az += vv * x.z; aw += vv * x.w;
  }
  if (raw_out) {
    float4 o; o.x = ax; o.y = ay; o.z = az; o.w = aw;
    *(float4*)(raw_out + (size_t)row * raw_str + lane_in * 4) = o;
  }
  if (scaled_out) {
    float t = (row < NU) ? ut[row] : it[row - NU];
    float sc = t;
    for (int j = 0; j < hop; ++j) sc *= (1.f - t);
    float4 o; o.x = ax * sc; o.y = ay * sc; o.z = az * sc; o.w = aw * sc;
    *(float4*)(scaled_out + (size_t)row * scaled_str + lane_in * 4) = o;
  }
}

// Fallback epilogue: scale slots 0..2 in place by t*(1-t)^k.
__global__ void epilogue_kernel(const float* __restrict__ ut, const float* __restrict__ it,
                                float* __restrict__ out) {
  int idx = blockIdx.x * blockDim.x + threadIdx.x;  // float4 units, NN * 96 total
  if (idx >= NN * 96) return;
  int node = idx / 96;
  int rem = idx - node * 96;
  int k = rem >> 5;        // slot 0..2
  int d4 = rem & 31;
  float t = (node < NU) ? ut[node] : it[node - NU];
  float dcy = 1.f - t;
  float sc = t;
  for (int j = 0; j < k; ++j) sc *= dcy;
  float4* p = (float4*)(out + (size_t)node * STR + k * DIM) + d4;
  float4 x = *p;
  x.x *= sc; x.y *= sc; x.z *= sc; x.w *= sc;
  *p = x;
}

// ---------------- launch ----------------

extern "C" void kernel_launch(void* const* d_in, const int* in_sizes, int n_in,
                              void* d_out, int out_size, void* d_ws, size_t ws_size,
                              hipStream_t stream) {
  const float* ue = (const float*)d_in[0];
  const float* ie = (const float*)d_in[1];
  const float* ut = (const float*)d_in[2];
  const float* it = (const float*)d_in[3];
  const float* vals = (const float*)d_in[4];
  const int* rows = (const int*)d_in[5];
  const int* cols = (const int*)d_in[6];
  float* out = (float*)d_out;
  const int E = in_sizes[4];

  size_t off = 0;
  auto alloc = [&](size_t bytes) {
    void* p = (char*)d_ws + off;
    off += (bytes + 255) & ~(size_t)255;
    return p;
  };
  int* deg = (int*)alloc((size_t)NN * 4);
  int* cursor = (int*)alloc((size_t)NN * 4);
  int* rstart = (int*)alloc(((size_t)NN + 1) * 4);
  int* bsum = (int*)alloc(1024 * 4);
  int* bdeg = (int*)alloc((size_t)NBINS * 4);
  int* boff = (int*)alloc(((size_t)NBINS + 1) * 4);
  int* bcursor = (int*)alloc((size_t)NBINS * 4);
  int2* csr = (int2*)alloc((size_t)E * 8);
  size_t csr_end = off;
  float* rawA = (float*)alloc((size_t)NN * DIM * 4);
  float* rawB = (float*)alloc((size_t)NN * DIM * 4);
  bool use_csr = (csr_end <= ws_size);
  bool use_compact = (off <= ws_size);

  // bucket arrays alias rawA (dead until copy_embed_fused): 19.2 + 38.4 <= 76.8 MB
  int* brow = (int*)rawA;
  int2* bcv = (int2*)((char*)rawA + ((size_t)E * 4 + 255 & ~(size_t)255));

  const int n4_embed = NN * (DIM / 4);
  const int nb_scan = (NN + 2047) / 2048;
  const int nb_scan_b = (NBINS + 2047) / 2048;   // 5
  const int spmm_blocks = (NN / 2 + 3) / 4;      // 4 waves/block, 2 rows/wave

  if (use_csr) {
    if (use_compact) {
      // ---- bucketed CSR build ----
      hipMemsetAsync(bdeg, 0, (size_t)NBINS * 4, stream);
      bucket_hist<<<PART_GRID, 256, 0, stream>>>(rows, bdeg, E);
      scan_k1<<<nb_scan_b, 256, 0, stream>>>(bdeg, bsum, NBINS);
      scan_k2<<<1, 64, 0, stream>>>(bsum, nb_scan_b);
      scan_k3<<<nb_scan_b, 256, 0, stream>>>(bdeg, bsum, boff, bcursor, NBINS, E);
      bucket_scatter<<<PART_GRID, 256, 0, stream>>>(rows, cols, vals, bcursor, brow, bcv, E);
      deg_from_buckets<<<NBK, 256, 0, stream>>>(boff, brow, deg);
      scan_k1<<<nb_scan, 256, 0, stream>>>(deg, bsum, NN);
      scan_k2<<<1, 64, 0, stream>>>(bsum, nb_scan);
      scan_k3<<<nb_scan, 256, 0, stream>>>(deg, bsum, rstart, cursor, NN, E);
      csr_from_buckets<<<NBK, 256, 0, stream>>>(boff, brow, bcv, cursor, csr);

      // ---- dense hops: compact raw ping-pong in ws, scaled writes fused ----
      copy_embed_fused<<<(n4_embed + 255) / 256, 256, 0, stream>>>(ue, ie, ut, it, rawA, out);
      float* rin = rawA;
      float* rout = rawB;
      for (int h = 1; h <= NHOPS; ++h) {
        float* raw_dst = (h < NHOPS) ? rout : nullptr;  // last hop: no raw consumer
        spmm_kernel<<<spmm_blocks, 256, 0, stream>>>(rstart, csr, rin, DIM,
                                                     raw_dst, DIM,
                                                     out + h * DIM, STR, ut, it, h);
        float* tmp = rin; rin = rout; rout = tmp;
      }
    } else {
      // fallback: direct scatter CSR build + raw slots in d_out
      hipMemsetAsync(deg, 0, (size_t)NN * 4, stream);
      hist_kernel<<<2048, 256, 0, stream>>>(rows, deg, E);
      scan_k1<<<nb_scan, 256, 0, stream>>>(deg, bsum, NN);
      scan_k2<<<1, 64, 0, stream>>>(bsum, nb_scan);
      scan_k3<<<nb_scan, 256, 0, stream>>>(deg, bsum, rstart, cursor, NN, E);
      scatter_kernel<<<2048, 256, 0, stream>>>(rows, cols, vals, cursor, csr, E);

      copy_embed_raw<<<(n4_embed + 255) / 256, 256, 0, stream>>>(ue, ie, out);
      for (int h = 1; h <= NHOPS; ++h) {
        float* raw_dst = (h < NHOPS) ? (out + h * DIM) : nullptr;
        float* sc_dst = (h == NHOPS) ? (out + h * DIM) : nullptr;
        spmm_kernel<<<spmm_blocks, 256, 0, stream>>>(rstart, csr, out + (h - 1) * DIM, STR,
                                                     raw_dst, STR, sc_dst, STR, ut, it, h);
      }
      epilogue_kernel<<<(NN * 96 + 255) / 256, 256, 0, stream>>>(ut, it, out);
    }
  }
}

// Round 3
// 1877.325 us; speedup vs baseline: 1.0466x; 1.0042x over previous
//
#include <hip/hip_runtime.h>

// Problem constants (fixed by reference)
#define NU 100000
#define NI 50000
#define NN 150000          // NU + NI
#define DIM 128
#define NHOPS 3
#define STR ((NHOPS + 1) * DIM)   // 512 floats per node in d_out

// Bucketed CSR build: bucket = row>>7 (128 rows per bucket), 8 sub-cursors
// per bucket keyed by blockIdx&7 (approx. XCD) so each append region is
// written by one L2 -> full-line evictions, ~1x write amplification.
#define NBK 1172            // ceil(NN / 128)
#define NSUB 8
#define NBINS (NBK * NSUB)  // 9376
#define PART_GRID 1024      // bucket_hist and bucket_scatter MUST share this

// Non-temporal helpers: keep write-once data (d_out slots) and read-once
// streams out of L2/L3 so the spmm gather source stays cache-resident.
typedef float __attribute__((ext_vector_type(4))) vfloat4;

__device__ __forceinline__ void nt_store4(float* p, float a, float b, float c, float d) {
  vfloat4 v; v.x = a; v.y = b; v.z = c; v.w = d;
  __builtin_nontemporal_store(v, (vfloat4*)p);
}
__device__ __forceinline__ vfloat4 nt_load4(const float* p) {
  return __builtin_nontemporal_load((const vfloat4*)p);
}

// ---------------- CSR build (fallback path kernels) ----------------

__global__ void hist_kernel(const int* __restrict__ rows, int* deg, int E) {
  int i = blockIdx.x * blockDim.x + threadIdx.x;
  int stride = gridDim.x * blockDim.x;
  for (; i < E; i += stride) atomicAdd(&deg[rows[i]], 1);
}

__global__ void scatter_kernel(const int* __restrict__ rows, const int* __restrict__ cols,
                               const float* __restrict__ vals, int* cursor,
                               int2* __restrict__ csr, int E) {
  int i = blockIdx.x * blockDim.x + threadIdx.x;
  int stride = gridDim.x * blockDim.x;
  for (; i < E; i += stride) {
    int r = rows[i];
    int p = atomicAdd(&cursor[r], 1);
    int2 e; e.x = cols[i]; e.y = __float_as_int(vals[i]);
    csr[p] = e;
  }
}

// ---------------- scan machinery (shared) ----------------
// 3-kernel multi-block exclusive scan over n counters.
__global__ void scan_k1(const int* __restrict__ deg, int* bsum, int n) {
  __shared__ int red[256];
  int b = blockIdx.x, t = threadIdx.x;
  int base = b * 2048 + t * 8;
  int s = 0;
#pragma unroll
  for (int j = 0; j < 8; ++j) { int i = base + j; if (i < n) s += deg[i]; }
  red[t] = s;
  __syncthreads();
  for (int off = 128; off > 0; off >>= 1) {
    if (t < off) red[t] += red[t + off];
    __syncthreads();
  }
  if (t == 0) bsum[b] = red[0];
}

__global__ void scan_k2(int* bsum, int nb) {
  if (threadIdx.x == 0) {
    int run = 0;
    for (int i = 0; i < nb; ++i) { int v = bsum[i]; bsum[i] = run; run += v; }
  }
}

__global__ void scan_k3(const int* __restrict__ deg, const int* __restrict__ bsum,
                        int* __restrict__ rstart, int* __restrict__ cursor, int n, int E) {
  __shared__ int red[256];
  int b = blockIdx.x, t = threadIdx.x;
  int base = b * 2048 + t * 8;
  int loc[8];
  int s = 0;
#pragma unroll
  for (int j = 0; j < 8; ++j) {
    int i = base + j;
    int d = (i < n) ? deg[i] : 0;
    loc[j] = s; s += d;
  }
  red[t] = s;
  __syncthreads();
  for (int off = 1; off < 256; off <<= 1) {
    int v = (t >= off) ? red[t - off] : 0;
    __syncthreads();
    red[t] += v;
    __syncthreads();
  }
  int toff = bsum[b] + red[t] - s;  // exclusive prefix for this thread
#pragma unroll
  for (int j = 0; j < 8; ++j) {
    int i = base + j;
    if (i < n) { int v = toff + loc[j]; rstart[i] = v; cursor[i] = v; }
  }
  if (b == 0 && t == 0) rstart[n] = E;
}

// ---------------- bucketed CSR build (primary path) ----------------

// Per-(bucket,sub) histogram. LDS-privatized per block; sub = blockIdx&7.
// Grid MUST match bucket_scatter (same edge->block mapping => same sub).
__global__ void bucket_hist(const int* __restrict__ rows, int* bdeg, int E) {
  __shared__ int h[NBK];
  for (int j = threadIdx.x; j < NBK; j += blockDim.x) h[j] = 0;
  __syncthreads();
  int i = blockIdx.x * blockDim.x + threadIdx.x;
  int stride = gridDim.x * blockDim.x;
  for (; i < E; i += stride) atomicAdd(&h[rows[i] >> 7], 1);
  __syncthreads();
  int sub = blockIdx.x & (NSUB - 1);
  for (int j = threadIdx.x; j < NBK; j += blockDim.x) {
    int v = h[j];
    if (v) atomicAdd(&bdeg[j * NSUB + sub], v);
  }
}

// Append edges into their (bucket,sub) region. Appends hit ~9K hot lines
// (L2-resident), each region written by one XCD -> full-line evictions.
__global__ void bucket_scatter(const int* __restrict__ rows, const int* __restrict__ cols,
                               const float* __restrict__ vals, int* bcursor,
                               int* __restrict__ brow, int2* __restrict__ bcv, int E) {
  int sub = blockIdx.x & (NSUB - 1);
  int i = blockIdx.x * blockDim.x + threadIdx.x;
  int stride = gridDim.x * blockDim.x;
  for (; i < E; i += stride) {
    int r = rows[i];
    int p = atomicAdd(&bcursor[(r >> 7) * NSUB + sub], 1);
    brow[p] = r;
    int2 e2; e2.x = cols[i]; e2.y = __float_as_int(vals[i]);
    bcv[p] = e2;
  }
}

// Row degrees via per-bucket LDS histogram; zero global atomics.
// Block b owns rows [b*128, b*128+128) exclusively.
__global__ void deg_from_buckets(const int* __restrict__ boff, const int* __restrict__ brow,
                                 int* __restrict__ deg) {
  __shared__ int h[128];
  int b = blockIdx.x;
  if (threadIdx.x < 128) h[threadIdx.x] = 0;
  __syncthreads();
  int base = b * 128;
  int s = boff[b * NSUB];
  int e = boff[b * NSUB + NSUB];
  for (int i = s + threadIdx.x; i < e; i += blockDim.x)
    atomicAdd(&h[brow[i] - base], 1);
  __syncthreads();
  if (threadIdx.x < 128) {
    int r = base + threadIdx.x;
    if (r < NN) deg[r] = h[threadIdx.x];
  }
}

// Final placement: block b reads its bucket segment sequentially and
// scatters within its private ~32KB CSR window (L2-local atomics+stores).
__global__ void csr_from_buckets(const int* __restrict__ boff, const int* __restrict__ brow,
                                 const int2* __restrict__ bcv, int* cursor,
                                 int2* __restrict__ csr) {
  int b = blockIdx.x;
  int s = boff[b * NSUB];
  int e = boff[b * NSUB + NSUB];
  for (int i = s + threadIdx.x; i < e; i += blockDim.x) {
    int r = brow[i];
    int p = atomicAdd(&cursor[r], 1);
    csr[p] = bcv[i];
  }
}

// ---------------- dense kernels ----------------

// raw concat -> rawA (stride DIM, compact, NORMAL store: hop-1 gather src);
// scaled ego (t*embed) -> out slot 0 (NT store: never read again).
__global__ void copy_embed_fused(const float* __restrict__ ue, const float* __restrict__ ie,
                                 const float* __restrict__ ut, const float* __restrict__ it,
                                 float* __restrict__ rawA, float* __restrict__ out) {
  int idx = blockIdx.x * blockDim.x + threadIdx.x;  // float4 index, NN*DIM/4 total
  if (idx >= NN * (DIM / 4)) return;
  int node = idx >> 5;   // 32 float4 per node
  int d4 = idx & 31;
  float t;
  vfloat4 x;
  if (node < NU) { t = ut[node]; x = nt_load4(ue + (size_t)node * DIM + d4 * 4); }
  else { t = it[node - NU]; x = nt_load4(ie + (size_t)(node - NU) * DIM + d4 * 4); }
  *(vfloat4*)(rawA + (size_t)node * DIM + d4 * 4) = x;
  nt_store4(out + (size_t)node * STR + d4 * 4, x.x * t, x.y * t, x.z * t, x.w * t);
}

// Fallback: raw concat -> out slot 0 only (epilogue scales later).
__global__ void copy_embed_raw(const float* __restrict__ ue, const float* __restrict__ ie,
                               float* __restrict__ out) {
  int idx = blockIdx.x * blockDim.x + threadIdx.x;
  if (idx >= NN * (DIM / 4)) return;
  int node = idx >> 5;
  int d4 = idx & 31;
  const float4* src = (node < NU)
      ? ((const float4*)(ue + (size_t)node * DIM) + d4)
      : ((const float4*)(ie + (size_t)(node - NU) * DIM) + d4);
  ((float4*)(out + (size_t)node * STR))[d4] = *src;
}

// 2 rows per wave: each 32-lane half owns one row, lane owns 4 dims (float4).
// Gather loads + CSR reads: normal caching (want L3 residency for src/CSR).
// scaled_out -> d_out: NT store (write-once), protects L3 from pollution.
// raw_out -> next hop's gather src: normal store.
__global__ __launch_bounds__(256) void spmm_kernel(
    const int* __restrict__ row_start, const int2* __restrict__ csr,
    const float* __restrict__ src, int src_str,
    float* raw_out, int raw_str,
    float* scaled_out, int scaled_str,
    const float* __restrict__ ut, const float* __restrict__ it, int hop) {
  int wave = (blockIdx.x * blockDim.x + threadIdx.x) >> 6;
  if (wave >= NN / 2) return;   // wave-uniform exit (NN is even)
  int lane = threadIdx.x & 63;
  int half = lane >> 5;         // which row of the pair this lane serves
  int lane_in = lane & 31;      // lane within half; owns dims [4*lane_in, 4*lane_in+4)
  int row = wave * 2 + half;
  int s = row_start[row];
  int e = row_start[row + 1];
  float ax = 0.f, ay = 0.f, az = 0.f, aw = 0.f;
  const float* src_base = src + lane_in * 4;
  int p = s;
  for (; p + 8 <= e; p += 8) {
    int2 ed = csr[p + (lane_in & 7)];
#pragma unroll
    for (int j = 0; j < 8; ++j) {
      int cc = __shfl(ed.x, j, 32);                     // broadcast within half
      float vv = __int_as_float(__shfl(ed.y, j, 32));
      float4 x = *(const float4*)(src_base + (size_t)cc * src_str);
      ax += vv * x.x; ay += vv * x.y; az += vv * x.z; aw += vv * x.w;
    }
  }
  for (; p < e; ++p) {
    int2 ed = csr[p];           // uniform within half -> broadcast load
    float4 x = *(const float4*)(src_base + (size_t)ed.x * src_str);
    float vv = __int_as_float(ed.y);
    ax += vv * x.x; ay += vv * x.y; az += vv * x.z; aw += vv * x.w;
  }
  if (raw_out) {
    float4 o; o.x = ax; o.y = ay; o.z = az; o.w = aw;
    *(float4*)(raw_out + (size_t)row * raw_str + lane_in * 4) = o;
  }
  if (scaled_out) {
    float t = (row < NU) ? ut[row] : it[row - NU];
    float sc = t;
    for (int j = 0; j < hop; ++j) sc *= (1.f - t);
    nt_store4(scaled_out + (size_t)row * scaled_str + lane_in * 4,
              ax * sc, ay * sc, az * sc, aw * sc);
  }
}

// Fallback epilogue: scale slots 0..2 in place by t*(1-t)^k.
__global__ void epilogue_kernel(const float* __restrict__ ut, const float* __restrict__ it,
                                float* __restrict__ out) {
  int idx = blockIdx.x * blockDim.x + threadIdx.x;  // float4 units, NN * 96 total
  if (idx >= NN * 96) return;
  int node = idx / 96;
  int rem = idx - node * 96;
  int k = rem >> 5;        // slot 0..2
  int d4 = rem & 31;
  float t = (node < NU) ? ut[node] : it[node - NU];
  float dcy = 1.f - t;
  float sc = t;
  for (int j = 0; j < k; ++j) sc *= dcy;
  float4* p = (float4*)(out + (size_t)node * STR + k * DIM) + d4;
  float4 x = *p;
  x.x *= sc; x.y *= sc; x.z *= sc; x.w *= sc;
  *p = x;
}

// ---------------- launch ----------------

extern "C" void kernel_launch(void* const* d_in, const int* in_sizes, int n_in,
                              void* d_out, int out_size, void* d_ws, size_t ws_size,
                              hipStream_t stream) {
  const float* ue = (const float*)d_in[0];
  const float* ie = (const float*)d_in[1];
  const float* ut = (const float*)d_in[2];
  const float* it = (const float*)d_in[3];
  const float* vals = (const float*)d_in[4];
  const int* rows = (const int*)d_in[5];
  const int* cols = (const int*)d_in[6];
  float* out = (float*)d_out;
  const int E = in_sizes[4];

  size_t off = 0;
  auto alloc = [&](size_t bytes) {
    void* p = (char*)d_ws + off;
    off += (bytes + 255) & ~(size_t)255;
    return p;
  };
  int* deg = (int*)alloc((size_t)NN * 4);
  int* cursor = (int*)alloc((size_t)NN * 4);
  int* rstart = (int*)alloc(((size_t)NN + 1) * 4);
  int* bsum = (int*)alloc(1024 * 4);
  int* bdeg = (int*)alloc((size_t)NBINS * 4);
  int* boff = (int*)alloc(((size_t)NBINS + 1) * 4);
  int* bcursor = (int*)alloc((size_t)NBINS * 4);
  int2* csr = (int2*)alloc((size_t)E * 8);
  size_t csr_end = off;
  float* rawA = (float*)alloc((size_t)NN * DIM * 4);
  float* rawB = (float*)alloc((size_t)NN * DIM * 4);
  bool use_csr = (csr_end <= ws_size);
  bool use_compact = (off <= ws_size);

  // bucket arrays alias rawA (dead until copy_embed_fused): 19.2 + 38.4 <= 76.8 MB
  int* brow = (int*)rawA;
  int2* bcv = (int2*)((char*)rawA + ((size_t)E * 4 + 255 & ~(size_t)255));

  const int n4_embed = NN * (DIM / 4);
  const int nb_scan = (NN + 2047) / 2048;
  const int nb_scan_b = (NBINS + 2047) / 2048;   // 5
  const int spmm_blocks = (NN / 2 + 3) / 4;      // 4 waves/block, 2 rows/wave

  if (use_csr) {
    if (use_compact) {
      // ---- bucketed CSR build ----
      hipMemsetAsync(bdeg, 0, (size_t)NBINS * 4, stream);
      bucket_hist<<<PART_GRID, 256, 0, stream>>>(rows, bdeg, E);
      scan_k1<<<nb_scan_b, 256, 0, stream>>>(bdeg, bsum, NBINS);
      scan_k2<<<1, 64, 0, stream>>>(bsum, nb_scan_b);
      scan_k3<<<nb_scan_b, 256, 0, stream>>>(bdeg, bsum, boff, bcursor, NBINS, E);
      bucket_scatter<<<PART_GRID, 256, 0, stream>>>(rows, cols, vals, bcursor, brow, bcv, E);
      deg_from_buckets<<<NBK, 256, 0, stream>>>(boff, brow, deg);
      scan_k1<<<nb_scan, 256, 0, stream>>>(deg, bsum, NN);
      scan_k2<<<1, 64, 0, stream>>>(bsum, nb_scan);
      scan_k3<<<nb_scan, 256, 0, stream>>>(deg, bsum, rstart, cursor, NN, E);
      csr_from_buckets<<<NBK, 256, 0, stream>>>(boff, brow, bcv, cursor, csr);

      // ---- dense hops: compact raw ping-pong in ws, scaled writes fused ----
      copy_embed_fused<<<(n4_embed + 255) / 256, 256, 0, stream>>>(ue, ie, ut, it, rawA, out);
      float* rin = rawA;
      float* rout = rawB;
      for (int h = 1; h <= NHOPS; ++h) {
        float* raw_dst = (h < NHOPS) ? rout : nullptr;  // last hop: no raw consumer
        spmm_kernel<<<spmm_blocks, 256, 0, stream>>>(rstart, csr, rin, DIM,
                                                     raw_dst, DIM,
                                                     out + h * DIM, STR, ut, it, h);
        float* tmp = rin; rin = rout; rout = tmp;
      }
    } else {
      // fallback: direct scatter CSR build + raw slots in d_out
      hipMemsetAsync(deg, 0, (size_t)NN * 4, stream);
      hist_kernel<<<2048, 256, 0, stream>>>(rows, deg, E);
      scan_k1<<<nb_scan, 256, 0, stream>>>(deg, bsum, NN);
      scan_k2<<<1, 64, 0, stream>>>(bsum, nb_scan);
      scan_k3<<<nb_scan, 256, 0, stream>>>(deg, bsum, rstart, cursor, NN, E);
      scatter_kernel<<<2048, 256, 0, stream>>>(rows, cols, vals, cursor, csr, E);

      copy_embed_raw<<<(n4_embed + 255) / 256, 256, 0, stream>>>(ue, ie, out);
      for (int h = 1; h <= NHOPS; ++h) {
        float* raw_dst = (h < NHOPS) ? (out + h * DIM) : nullptr;
        float* sc_dst = (h == NHOPS) ? (out + h * DIM) : nullptr;
        spmm_kernel<<<spmm_blocks, 256, 0, stream>>>(rstart, csr, out + (h - 1) * DIM, STR,
                                                     raw_dst, STR, sc_dst, STR, ut, it, h);
      }
      epilogue_kernel<<<(NN * 96 + 255) / 256, 256, 0, stream>>>(ut, it, out);
    }
  }
}